// Round 5
// baseline (944.940 us; speedup 1.0000x reference)
//
#include <hip/hip_runtime.h>

#define NN 100000
#define NG 64

// ======================= shared GEMM body: 64x64 tile, U = x @ W[by] ========
__device__ __forceinline__ void gemmU_body(const float* __restrict__ x,
                                           const float* __restrict__ W,
                                           float* __restrict__ U, int N,
                                           int bx, int by) {
    __shared__ float As[16][68];
    __shared__ float Bs[16][64];
    const float* Wk = W + by * (128 * 64);
    int row0 = bx * 64;
    int tid = threadIdx.x;
    int tr = tid >> 4, tc = tid & 15;
    float acc[4][4] = {};
    for (int k0 = 0; k0 < 128; k0 += 16) {
        {
            int r = row0 + (tid >> 2);
            int cc = (tid & 3) * 4;
            float4 v = make_float4(0.f, 0.f, 0.f, 0.f);
            if (r < N) v = *reinterpret_cast<const float4*>(x + (size_t)r * 128 + k0 + cc);
            As[cc + 0][tid >> 2] = v.x;
            As[cc + 1][tid >> 2] = v.y;
            As[cc + 2][tid >> 2] = v.z;
            As[cc + 3][tid >> 2] = v.w;
        }
        {
            int rr = tid >> 4;
            int cc = (tid & 15) * 4;
            *reinterpret_cast<float4*>(&Bs[rr][cc]) =
                *reinterpret_cast<const float4*>(Wk + (k0 + rr) * 64 + cc);
        }
        __syncthreads();
#pragma unroll
        for (int kk = 0; kk < 16; ++kk) {
            float4 a = *reinterpret_cast<const float4*>(&As[kk][tr * 4]);
            float4 b = *reinterpret_cast<const float4*>(&Bs[kk][tc * 4]);
            acc[0][0] += a.x * b.x; acc[0][1] += a.x * b.y; acc[0][2] += a.x * b.z; acc[0][3] += a.x * b.w;
            acc[1][0] += a.y * b.x; acc[1][1] += a.y * b.y; acc[1][2] += a.y * b.z; acc[1][3] += a.y * b.w;
            acc[2][0] += a.z * b.x; acc[2][1] += a.z * b.y; acc[2][2] += a.z * b.z; acc[2][3] += a.z * b.w;
            acc[3][0] += a.w * b.x; acc[3][1] += a.w * b.y; acc[3][2] += a.w * b.z; acc[3][3] += a.w * b.w;
        }
        __syncthreads();
    }
    int cbase = by * 64;
#pragma unroll
    for (int i = 0; i < 4; ++i) {
        int r = row0 + tr * 4 + i;
        if (r >= N) continue;
#pragma unroll
        for (int j = 0; j < 4; ++j)
            U[(size_t)r * 192 + cbase + tc * 4 + j] = acc[i][j];
    }
}

// ====== pre1: edge blocks FIRST (deg atomic + hist atomic w/ rank), then ====
// ====== gemmU(y=0,1) blocks                                             ====
__global__ __launch_bounds__(256) void k_pre1(const float* __restrict__ x,
                                              const float* __restrict__ W1,
                                              float* __restrict__ U, int N,
                                              const int* __restrict__ src,
                                              const int* __restrict__ dst,
                                              const float* __restrict__ ew,
                                              float* __restrict__ deg,
                                              int* __restrict__ cnt,
                                              int* __restrict__ rank, int E,
                                              int eb, int gx) {
    int b = blockIdx.x;
    if (b < eb) {
        int e = b * 256 + threadIdx.x;
        if (e < E) {
            atomicAdd(&deg[src[e]], ew[e]);
            rank[e] = atomicAdd(&cnt[dst[e]], 1);
        }
    } else {
        int g = b - eb;
        gemmU_body(x, W1, U, N, g % gx, g / gx);
    }
}

// ====== pre2: fill blocks FIRST (no atomics), then gemmU(y=2) blocks ========
__global__ __launch_bounds__(256) void k_pre2(const float* __restrict__ x,
                                              const float* __restrict__ W1,
                                              float* __restrict__ U, int N,
                                              const int* __restrict__ src,
                                              const int* __restrict__ dst,
                                              const float* __restrict__ ew,
                                              const float* __restrict__ dinv,
                                              const int* __restrict__ starts,
                                              const int* __restrict__ rank,
                                              int2* __restrict__ csr, int E,
                                              int eb, int gx) {
    int b = blockIdx.x;
    if (b < eb) {
        int e = b * 256 + threadIdx.x;
        if (e < E) {
            int s = src[e], d = dst[e];
            int pos = starts[d] + rank[e];
            float w = -dinv[s] * ew[e] * dinv[d];
            csr[pos] = make_int2(s, __float_as_int(w));
        }
    } else {
        gemmU_body(x, W1, U, N, b - eb, 2);
    }
}

// ================= scan pass A (+ fused dinv) =================
__global__ __launch_bounds__(1024) void k_scan_a(int* __restrict__ cnt,
                                                 int* __restrict__ bsum,
                                                 float* __restrict__ deg, int N) {
    __shared__ int sh[1024];
    int t = threadIdx.x;
    int idx = blockIdx.x * 1024 + t;
    int v = (idx < N) ? cnt[idx] : 0;
    if (idx < N) {
        float d = deg[idx];
        deg[idx] = (d > 0.f) ? rsqrtf(fmaxf(d, 1e-30f)) : 0.f;
    }
    sh[t] = v;
    __syncthreads();
#pragma unroll
    for (int off = 1; off < 1024; off <<= 1) {
        int tmp = (t >= off) ? sh[t - off] : 0;
        __syncthreads();
        sh[t] += tmp;
        __syncthreads();
    }
    if (idx < N) cnt[idx] = sh[t] - v;  // exclusive
    if (t == 1023) bsum[blockIdx.x] = sh[1023];
}

__global__ __launch_bounds__(128) void k_scan_b(const int* __restrict__ bsum,
                                                int* __restrict__ boff, int nb) {
    __shared__ int sh[128];
    int t = threadIdx.x;
    int v = (t < nb) ? bsum[t] : 0;
    sh[t] = v;
    __syncthreads();
#pragma unroll
    for (int off = 1; off < 128; off <<= 1) {
        int tmp = (t >= off) ? sh[t - off] : 0;
        __syncthreads();
        sh[t] += tmp;
        __syncthreads();
    }
    if (t < nb) boff[t] = sh[t] - v;
}

__global__ __launch_bounds__(1024) void k_scan_c(int* __restrict__ cnt,
                                                 const int* __restrict__ boff,
                                                 int N, int E) {
    int idx = blockIdx.x * 1024 + threadIdx.x;
    if (idx < N) cnt[idx] += boff[blockIdx.x];
    if (idx == 0) cnt[N] = E;  // sentinel row end
}

// ================= propagation (CSR gather, packed int2) =================
// rs = row starts (N+1). MODE 0: out=acc; MODE 1: out=2*acc-t0;
// MODE 2: out = relu(u0 + p1 + 2*acc - u2 + bias)
template <int F, int MODE>
__global__ __launch_bounds__(256) void k_prop_csr(const int* __restrict__ rs,
                                                  const int2* __restrict__ csr,
                                                  const float* __restrict__ in,
                                                  int istride,
                                                  float* __restrict__ out,
                                                  int ostride,
                                                  const float* __restrict__ t0,
                                                  const float* __restrict__ u0,
                                                  const float* __restrict__ u2,
                                                  const float* __restrict__ p1,
                                                  const float* __restrict__ bias,
                                                  int N) {
    const int CPE = F / 4;
    int tid = blockIdx.x * 256 + threadIdx.x;
    int node = tid / CPE;
    int lane = tid % CPE;
    if (node >= N) return;
    int start = rs[node];
    int end = rs[node + 1];
    float4 acc = make_float4(0.f, 0.f, 0.f, 0.f);
    int c4 = lane * 4;
    int j = start;
    for (; j + 4 <= end; j += 4) {
        int2 e0 = csr[j + 0], e1 = csr[j + 1], e2 = csr[j + 2], e3 = csr[j + 3];
        float w0 = __int_as_float(e0.y), w1 = __int_as_float(e1.y);
        float w2 = __int_as_float(e2.y), w3 = __int_as_float(e3.y);
        float4 v0 = *reinterpret_cast<const float4*>(in + (size_t)e0.x * istride + c4);
        float4 v1 = *reinterpret_cast<const float4*>(in + (size_t)e1.x * istride + c4);
        float4 v2 = *reinterpret_cast<const float4*>(in + (size_t)e2.x * istride + c4);
        float4 v3 = *reinterpret_cast<const float4*>(in + (size_t)e3.x * istride + c4);
        acc.x += w0 * v0.x + w1 * v1.x + w2 * v2.x + w3 * v3.x;
        acc.y += w0 * v0.y + w1 * v1.y + w2 * v2.y + w3 * v3.y;
        acc.z += w0 * v0.z + w1 * v1.z + w2 * v2.z + w3 * v3.z;
        acc.w += w0 * v0.w + w1 * v1.w + w2 * v2.w + w3 * v3.w;
    }
    for (; j < end; ++j) {
        int2 e0 = csr[j];
        float w0 = __int_as_float(e0.y);
        float4 v0 = *reinterpret_cast<const float4*>(in + (size_t)e0.x * istride + c4);
        acc.x += w0 * v0.x;
        acc.y += w0 * v0.y;
        acc.z += w0 * v0.z;
        acc.w += w0 * v0.w;
    }
    float4 r;
    if (MODE == 0) {
        r = acc;
    } else if (MODE == 1) {
        float4 t = *reinterpret_cast<const float4*>(t0 + (size_t)node * 64 + c4);
        r.x = 2.f * acc.x - t.x;
        r.y = 2.f * acc.y - t.y;
        r.z = 2.f * acc.z - t.z;
        r.w = 2.f * acc.w - t.w;
    } else {
        float4 a = *reinterpret_cast<const float4*>(u0 + (size_t)node * 192 + c4);
        float4 b = *reinterpret_cast<const float4*>(u2 + (size_t)node * 192 + c4);
        float4 p = *reinterpret_cast<const float4*>(p1 + (size_t)node * 128 + c4);
        float4 bb = *reinterpret_cast<const float4*>(bias + c4);
        r.x = fmaxf(a.x + p.x + 2.f * acc.x - b.x + bb.x, 0.f);
        r.y = fmaxf(a.y + p.y + 2.f * acc.y - b.y + bb.y, 0.f);
        r.z = fmaxf(a.z + p.z + 2.f * acc.z - b.z + bb.z, 0.f);
        r.w = fmaxf(a.w + p.w + 2.f * acc.w - b.w + bb.w, 0.f);
    }
    *reinterpret_cast<float4*>(out + (size_t)node * ostride + c4) = r;
}

// ====== 3-term GEMM: out = relu(T0@W0 + T1@W1 + T2@W2 + b); optional pool ===
template <bool POOL>
__global__ __launch_bounds__(256) void k_gemm3(const float* __restrict__ T0,
                                               const float* __restrict__ T1,
                                               const float* __restrict__ T2,
                                               const float* __restrict__ W,
                                               const float* __restrict__ bias,
                                               float* __restrict__ out,
                                               int N, int Fin, int Fout,
                                               const int* __restrict__ batch,
                                               float* __restrict__ sums) {
    __shared__ float As[16][68];
    __shared__ float Bs[16][64];
    int row0 = blockIdx.x * 64;
    int col0 = blockIdx.y * 64;
    int tid = threadIdx.x;
    int tr = tid >> 4, tc = tid & 15;
    float acc[4][4] = {};
    const float* Ts[3] = {T0, T1, T2};
    for (int k = 0; k < 3; ++k) {
        const float* T = Ts[k];
        const float* Wk = W + k * Fin * Fout;
        for (int k0 = 0; k0 < Fin; k0 += 16) {
            {
                int r = row0 + (tid >> 2);
                int cc = (tid & 3) * 4;
                float4 v = make_float4(0.f, 0.f, 0.f, 0.f);
                if (r < N)
                    v = *reinterpret_cast<const float4*>(T + (size_t)r * Fin + k0 + cc);
                As[cc + 0][tid >> 2] = v.x;
                As[cc + 1][tid >> 2] = v.y;
                As[cc + 2][tid >> 2] = v.z;
                As[cc + 3][tid >> 2] = v.w;
            }
            {
                int rr = tid >> 4;
                int cc = (tid & 15) * 4;
                *reinterpret_cast<float4*>(&Bs[rr][cc]) =
                    *reinterpret_cast<const float4*>(Wk + (size_t)(k0 + rr) * Fout + col0 + cc);
            }
            __syncthreads();
#pragma unroll
            for (int kk = 0; kk < 16; ++kk) {
                float4 a = *reinterpret_cast<const float4*>(&As[kk][tr * 4]);
                float4 b = *reinterpret_cast<const float4*>(&Bs[kk][tc * 4]);
                acc[0][0] += a.x * b.x; acc[0][1] += a.x * b.y; acc[0][2] += a.x * b.z; acc[0][3] += a.x * b.w;
                acc[1][0] += a.y * b.x; acc[1][1] += a.y * b.y; acc[1][2] += a.y * b.z; acc[1][3] += a.y * b.w;
                acc[2][0] += a.z * b.x; acc[2][1] += a.z * b.y; acc[2][2] += a.z * b.z; acc[2][3] += a.z * b.w;
                acc[3][0] += a.w * b.x; acc[3][1] += a.w * b.y; acc[3][2] += a.w * b.z; acc[3][3] += a.w * b.w;
            }
            __syncthreads();
        }
    }
    if (!POOL) {
#pragma unroll
        for (int i = 0; i < 4; ++i) {
            int r = row0 + tr * 4 + i;
            if (r >= N) continue;
#pragma unroll
            for (int j = 0; j < 4; ++j) {
                int cgl = col0 + tc * 4 + j;
                out[(size_t)r * Fout + cgl] = fmaxf(acc[i][j] + bias[cgl], 0.f);
            }
        }
    } else {
        __shared__ float ps[64];
        int b0 = batch[row0];
        int b1v = batch[min(row0 + 63, N - 1)];
        if (b0 == b1v) {
            if (tid < 64) ps[tid] = 0.f;
            __syncthreads();
#pragma unroll
            for (int j = 0; j < 4; ++j) {
                float cs = 0.f;
#pragma unroll
                for (int i = 0; i < 4; ++i) {
                    int r = row0 + tr * 4 + i;
                    if (r < N) cs += fmaxf(acc[i][j] + bias[col0 + tc * 4 + j], 0.f);
                }
                atomicAdd(&ps[tc * 4 + j], cs);
            }
            __syncthreads();
            if (tid < 64) atomicAdd(&sums[b0 * 128 + col0 + tid], ps[tid]);
        } else {
#pragma unroll
            for (int i = 0; i < 4; ++i) {
                int r = row0 + tr * 4 + i;
                if (r >= N) continue;
#pragma unroll
                for (int j = 0; j < 4; ++j) {
                    int cgl = col0 + tc * 4 + j;
                    float v = fmaxf(acc[i][j] + bias[cgl], 0.f);
                    atomicAdd(&sums[batch[r] * 128 + cgl], v);
                }
            }
        }
    }
}

// ================= head (graph starts computed in-kernel) =================
__global__ __launch_bounds__(640) void k_head(const float* __restrict__ sums,
                                              const int* __restrict__ batch, int N,
                                              const float* __restrict__ linW,
                                              const float* __restrict__ linb,
                                              float* __restrict__ out) {
    __shared__ int st[65];
    int t = threadIdx.x;
    if (t <= 64) {
        if (t == 64) {
            st[64] = N;
        } else {
            int lo = 0, hi = N;
            while (lo < hi) {
                int mid = (lo + hi) >> 1;
                if (batch[mid] < t) lo = mid + 1; else hi = mid;
            }
            st[t] = lo;
        }
    }
    __syncthreads();
    if (t >= NG * 10) return;
    int g = t / 10, o = t % 10;
    float cnt = (float)(st[g + 1] - st[g]);
    float inv = 1.f / fmaxf(cnt, 1.f);
    float acc = 0.f;
#pragma unroll 8
    for (int k = 0; k < 128; ++k) acc += sums[g * 128 + k] * linW[k * 10 + o];
    out[t] = acc * inv + linb[o];
}

// ================= launch =================
extern "C" void kernel_launch(void* const* d_in, const int* in_sizes, int n_in,
                              void* d_out, int out_size, void* d_ws, size_t ws_size,
                              hipStream_t stream) {
    const float* x = (const float*)d_in[0];
    const int* ei = (const int*)d_in[1];
    const float* ew = (const float*)d_in[2];
    const int* batch = (const int*)d_in[3];
    const float* W1 = (const float*)d_in[4];
    const float* b1 = (const float*)d_in[5];
    const float* W2 = (const float*)d_in[6];
    const float* b2 = (const float*)d_in[7];
    const float* W3 = (const float*)d_in[8];
    const float* b3 = (const float*)d_in[9];
    const float* linW = (const float*)d_in[10];
    const float* linb = (const float*)d_in[11];

    const int E = in_sizes[1] / 2;   // 1,600,000
    const int N = in_sizes[0] / 128; // 100,000
    const int* src = ei;
    const int* dst = ei + E;

    float* ws = (float*)d_ws;
    int2*  csr     = (int2*)ws;                        // E entries (8B) -> 3,200,512 f
    int*   rank    = (int*)(ws + 3200512);             // 1,600,256
    int*   cursor  = rank + 1600256;                   // N+1 -> 100,352 (starts)
    float* dinv    = (float*)(cursor + 100352);        // 100,352 (deg then dinv)
    int*   bsum    = (int*)(dinv + 100352);            // 256
    int*   boff    = bsum + 256;                       // 256
    float* U       = (float*)(boff + 256);             // 19,200,256 (N x 192)
    float* P12     = U + 19200256;                     // 12,800,256 (N x 128)
    float* H1      = P12 + 12800256;                   // 6,400,256  (N x 64)
    float* sums    = H1 + 6400256;                     // 8,192

    float* A2 = U;                  // layer-2 temporaries alias U (free by then)
    float* B2 = U + 6400256;
    float* H2 = U + 12800512;
    float* A3 = P12;                // layer-3 temporaries alias P12
    float* B3 = P12 + 6400256;

    const int TB = 256;
    auto blocks = [](long long t, int b) { return (int)((t + b - 1) / b); };
    const int PG64  = blocks((long long)N * 16, TB);
    const int PG128 = blocks((long long)N * 32, TB);
    const int NB = (N + 1023) / 1024;       // scan blocks
    const int GX = (N + 63) / 64;           // gemmU x-blocks
    const int EB = blocks(E, TB);           // edge blocks

    // ---- all memsets up front (cursor[N+1] + deg contiguous; sums) ----
    hipMemsetAsync(cursor, 0, (100352 + 100352) * sizeof(int), stream);
    hipMemsetAsync(sums, 0, NG * 128 * sizeof(float), stream);

    // ---- pre1: edges (deg + hist + rank) first, then gemmU(y0,y1) ----
    k_pre1<<<EB + 2 * GX, TB, 0, stream>>>(x, W1, U, N, src, dst, ew,
                                           dinv, cursor, rank, E, EB, GX);
    // ---- dinv + scan (cursor -> row starts; cursor[N]=E) ----
    k_scan_a<<<NB, 1024, 0, stream>>>(cursor, bsum, dinv, N);
    k_scan_b<<<1, 128, 0, stream>>>(bsum, boff, NB);
    k_scan_c<<<NB, 1024, 0, stream>>>(cursor, boff, N, E);
    // ---- pre2: fill (no atomics) first, then gemmU(y2) ----
    k_pre2<<<EB + GX, TB, 0, stream>>>(x, W1, U, N, src, dst, ew, dinv,
                                       cursor, rank, csr, E, EB, GX);

    // ---- layer 1: [P1|P2]=prop([U1|U2]); H1=relu(U0+P1+2*prop(P2)-U2+b1) ----
    k_prop_csr<128, 0><<<PG128, TB, 0, stream>>>(cursor, csr, U + 64, 192,
                                                 P12, 128, nullptr, nullptr, nullptr,
                                                 nullptr, nullptr, N);
    k_prop_csr<64, 2><<<PG64, TB, 0, stream>>>(cursor, csr, P12 + 64, 128,
                                               H1, 64, nullptr, U, U + 128, P12, b1, N);

    // ---- layer 2 ----
    k_prop_csr<64, 0><<<PG64, TB, 0, stream>>>(cursor, csr, H1, 64, A2, 64,
                                               nullptr, nullptr, nullptr, nullptr, nullptr, N);
    k_prop_csr<64, 1><<<PG64, TB, 0, stream>>>(cursor, csr, A2, 64, B2, 64,
                                               H1, nullptr, nullptr, nullptr, nullptr, N);
    {
        dim3 g(GX, 1);
        k_gemm3<false><<<g, TB, 0, stream>>>(H1, A2, B2, W2, b2, H2, N, 64, 64, nullptr, nullptr);
    }

    // ---- layer 3: props + GEMM fused with mean-pool sums ----
    k_prop_csr<64, 0><<<PG64, TB, 0, stream>>>(cursor, csr, H2, 64, A3, 64,
                                               nullptr, nullptr, nullptr, nullptr, nullptr, N);
    k_prop_csr<64, 1><<<PG64, TB, 0, stream>>>(cursor, csr, A3, 64, B3, 64,
                                               H2, nullptr, nullptr, nullptr, nullptr, N);
    {
        dim3 g(GX, 2);
        k_gemm3<true><<<g, TB, 0, stream>>>(H2, A3, B3, W3, b3, nullptr, N, 64, 128, batch, sums);
    }

    // ---- head ----
    k_head<<<1, 640, 0, stream>>>(sums, batch, N, linW, linb, (float*)d_out);
}

// Round 8
// 862.371 us; speedup vs baseline: 1.0957x; 1.0957x over previous
//
#include <hip/hip_runtime.h>

#define NN 100000
#define NG 64

// ======================= gemmU body: U[:,by*64:+64] = x @ Wsel ==============
// by==0 uses W[0]-W[2]; out stride 192. Fin=128.
__device__ __forceinline__ void gemmU_body(const float* __restrict__ x,
                                           const float* __restrict__ W,
                                           float* __restrict__ U, int N,
                                           int bx, int by) {
    __shared__ float As[16][68];
    __shared__ float Bs[16][64];
    const float* Wk = W + by * (128 * 64);
    const float* W2k = W + 2 * (128 * 64);
    int row0 = bx * 64;
    int tid = threadIdx.x;
    int tr = tid >> 4, tc = tid & 15;
    float acc[4][4] = {};
    for (int k0 = 0; k0 < 128; k0 += 16) {
        {
            int r = row0 + (tid >> 2);
            int cc = (tid & 3) * 4;
            float4 v = make_float4(0.f, 0.f, 0.f, 0.f);
            if (r < N) v = *reinterpret_cast<const float4*>(x + (size_t)r * 128 + k0 + cc);
            As[cc + 0][tid >> 2] = v.x;
            As[cc + 1][tid >> 2] = v.y;
            As[cc + 2][tid >> 2] = v.z;
            As[cc + 3][tid >> 2] = v.w;
        }
        {
            int rr = tid >> 4;
            int cc = (tid & 15) * 4;
            float4 v = *reinterpret_cast<const float4*>(Wk + (k0 + rr) * 64 + cc);
            if (by == 0) {
                float4 w2 = *reinterpret_cast<const float4*>(W2k + (k0 + rr) * 64 + cc);
                v.x -= w2.x; v.y -= w2.y; v.z -= w2.z; v.w -= w2.w;
            }
            *reinterpret_cast<float4*>(&Bs[rr][cc]) = v;
        }
        __syncthreads();
#pragma unroll
        for (int kk = 0; kk < 16; ++kk) {
            float4 a = *reinterpret_cast<const float4*>(&As[kk][tr * 4]);
            float4 b = *reinterpret_cast<const float4*>(&Bs[kk][tc * 4]);
            acc[0][0] += a.x * b.x; acc[0][1] += a.x * b.y; acc[0][2] += a.x * b.z; acc[0][3] += a.x * b.w;
            acc[1][0] += a.y * b.x; acc[1][1] += a.y * b.y; acc[1][2] += a.y * b.z; acc[1][3] += a.y * b.w;
            acc[2][0] += a.z * b.x; acc[2][1] += a.z * b.y; acc[2][2] += a.z * b.z; acc[2][3] += a.z * b.w;
            acc[3][0] += a.w * b.x; acc[3][1] += a.w * b.y; acc[3][2] += a.w * b.z; acc[3][3] += a.w * b.w;
        }
        __syncthreads();
    }
    int cbase = by * 64;
#pragma unroll
    for (int i = 0; i < 4; ++i) {
        int r = row0 + tr * 4 + i;
        if (r >= N) continue;
#pragma unroll
        for (int j = 0; j < 4; ++j)
            U[(size_t)r * 192 + cbase + tc * 4 + j] = acc[i][j];
    }
}

// ====== pre1: gemmU(y=0,1,2) blocks FIRST, then edges (deg+hist+rank) =======
__global__ __launch_bounds__(256) void k_pre1(const float* __restrict__ x,
                                              const float* __restrict__ W1,
                                              float* __restrict__ U, int N,
                                              const int* __restrict__ src,
                                              const int* __restrict__ dst,
                                              const float* __restrict__ ew,
                                              float* __restrict__ deg,
                                              int* __restrict__ cnt,
                                              int* __restrict__ rank, int E,
                                              int gx) {
    int b = blockIdx.x;
    if (b < 3 * gx) {
        gemmU_body(x, W1, U, N, b % gx, b / gx);
    } else {
        int e = (b - 3 * gx) * 256 + threadIdx.x;
        if (e < E) {
            atomicAdd(&deg[src[e]], ew[e]);
            rank[e] = atomicAdd(&cnt[dst[e]], 1);
        }
    }
}

// ====== fill (no atomics): pos = starts[dst] + rank ========================
__global__ __launch_bounds__(256) void k_fill(const int* __restrict__ src,
                                              const int* __restrict__ dst,
                                              const float* __restrict__ ew,
                                              const float* __restrict__ dinv,
                                              const int* __restrict__ starts,
                                              const int* __restrict__ rank,
                                              int2* __restrict__ csr, int E) {
    int e = blockIdx.x * 256 + threadIdx.x;
    if (e >= E) return;
    int s = src[e], d = dst[e];
    int pos = starts[d] + rank[e];
    float w = -dinv[s] * ew[e] * dinv[d];
    csr[pos] = make_int2(s, __float_as_int(w));
}

// ================= scan pass A (+ fused dinv) =================
__global__ __launch_bounds__(1024) void k_scan_a(int* __restrict__ cnt,
                                                 int* __restrict__ bsum,
                                                 float* __restrict__ deg, int N) {
    __shared__ int sh[1024];
    int t = threadIdx.x;
    int idx = blockIdx.x * 1024 + t;
    int v = (idx < N) ? cnt[idx] : 0;
    if (idx < N) {
        float d = deg[idx];
        deg[idx] = (d > 0.f) ? rsqrtf(fmaxf(d, 1e-30f)) : 0.f;
    }
    sh[t] = v;
    __syncthreads();
#pragma unroll
    for (int off = 1; off < 1024; off <<= 1) {
        int tmp = (t >= off) ? sh[t - off] : 0;
        __syncthreads();
        sh[t] += tmp;
        __syncthreads();
    }
    if (idx < N) cnt[idx] = sh[t] - v;  // exclusive
    if (t == 1023) bsum[blockIdx.x] = sh[1023];
}

__global__ __launch_bounds__(128) void k_scan_b(const int* __restrict__ bsum,
                                                int* __restrict__ boff, int nb) {
    __shared__ int sh[128];
    int t = threadIdx.x;
    int v = (t < nb) ? bsum[t] : 0;
    sh[t] = v;
    __syncthreads();
#pragma unroll
    for (int off = 1; off < 128; off <<= 1) {
        int tmp = (t >= off) ? sh[t - off] : 0;
        __syncthreads();
        sh[t] += tmp;
        __syncthreads();
    }
    if (t < nb) boff[t] = sh[t] - v;
}

__global__ __launch_bounds__(1024) void k_scan_c(int* __restrict__ cnt,
                                                 const int* __restrict__ boff,
                                                 int N, int E) {
    int idx = blockIdx.x * 1024 + threadIdx.x;
    if (idx < N) cnt[idx] += boff[blockIdx.x];
    if (idx == 0) cnt[N] = E;  // sentinel row end
}

// ================= propagation (CSR gather, F=64, packed int2) =============
// MODE 0: out = acc
// MODE 1: out = 2*acc - t0                      (layer-3 T2 step)
// MODE 3: out = t0 + 2*acc                      (R-step, t0 = U1/V1 slice)
// MODE 4: out = relu(t0 + acc + bias)           (H-step, t0 = U0'/V0' slice)
template <int MODE>
__global__ __launch_bounds__(256) void k_prop64(const int* __restrict__ rs,
                                                const int2* __restrict__ csr,
                                                const float* __restrict__ in,
                                                int istride,
                                                float* __restrict__ out,
                                                const float* __restrict__ t0,
                                                int t0s,
                                                const float* __restrict__ bias,
                                                int N) {
    int tid = blockIdx.x * 256 + threadIdx.x;
    int node = tid >> 4;
    int lane = tid & 15;
    if (node >= N) return;
    int start = rs[node];
    int end = rs[node + 1];
    float4 acc = make_float4(0.f, 0.f, 0.f, 0.f);
    int c4 = lane * 4;
    int j = start;
    for (; j + 4 <= end; j += 4) {
        int2 e0 = csr[j + 0], e1 = csr[j + 1], e2 = csr[j + 2], e3 = csr[j + 3];
        float w0 = __int_as_float(e0.y), w1 = __int_as_float(e1.y);
        float w2 = __int_as_float(e2.y), w3 = __int_as_float(e3.y);
        float4 v0 = *reinterpret_cast<const float4*>(in + (size_t)e0.x * istride + c4);
        float4 v1 = *reinterpret_cast<const float4*>(in + (size_t)e1.x * istride + c4);
        float4 v2 = *reinterpret_cast<const float4*>(in + (size_t)e2.x * istride + c4);
        float4 v3 = *reinterpret_cast<const float4*>(in + (size_t)e3.x * istride + c4);
        acc.x += w0 * v0.x + w1 * v1.x + w2 * v2.x + w3 * v3.x;
        acc.y += w0 * v0.y + w1 * v1.y + w2 * v2.y + w3 * v3.y;
        acc.z += w0 * v0.z + w1 * v1.z + w2 * v2.z + w3 * v3.z;
        acc.w += w0 * v0.w + w1 * v1.w + w2 * v2.w + w3 * v3.w;
    }
    for (; j < end; ++j) {
        int2 e0 = csr[j];
        float w0 = __int_as_float(e0.y);
        float4 v0 = *reinterpret_cast<const float4*>(in + (size_t)e0.x * istride + c4);
        acc.x += w0 * v0.x;
        acc.y += w0 * v0.y;
        acc.z += w0 * v0.z;
        acc.w += w0 * v0.w;
    }
    float4 r;
    if (MODE == 0) {
        r = acc;
    } else if (MODE == 1) {
        float4 t = *reinterpret_cast<const float4*>(t0 + (size_t)node * t0s + c4);
        r.x = 2.f * acc.x - t.x;
        r.y = 2.f * acc.y - t.y;
        r.z = 2.f * acc.z - t.z;
        r.w = 2.f * acc.w - t.w;
    } else if (MODE == 3) {
        float4 t = *reinterpret_cast<const float4*>(t0 + (size_t)node * t0s + c4);
        r.x = t.x + 2.f * acc.x;
        r.y = t.y + 2.f * acc.y;
        r.z = t.z + 2.f * acc.z;
        r.w = t.w + 2.f * acc.w;
    } else {
        float4 t = *reinterpret_cast<const float4*>(t0 + (size_t)node * t0s + c4);
        float4 bb = *reinterpret_cast<const float4*>(bias + c4);
        r.x = fmaxf(t.x + acc.x + bb.x, 0.f);
        r.y = fmaxf(t.y + acc.y + bb.y, 0.f);
        r.z = fmaxf(t.z + acc.z + bb.z, 0.f);
        r.w = fmaxf(t.w + acc.w + bb.w, 0.f);
    }
    *reinterpret_cast<float4*>(out + (size_t)node * 64 + c4) = r;
}

// ====== gemmD: V = H @ [W0-W2 | W1 | W2]  (Fin=64, out stride 192) =========
__global__ __launch_bounds__(256) void k_gemmD(const float* __restrict__ H,
                                               const float* __restrict__ W,
                                               float* __restrict__ V, int N) {
    __shared__ float As[16][68];
    __shared__ float Bs[16][64];
    int by = blockIdx.y;
    const float* Wk = W + by * (64 * 64);
    const float* W2k = W + 2 * (64 * 64);
    int row0 = blockIdx.x * 64;
    int tid = threadIdx.x;
    int tr = tid >> 4, tc = tid & 15;
    float acc[4][4] = {};
    for (int k0 = 0; k0 < 64; k0 += 16) {
        {
            int r = row0 + (tid >> 2);
            int cc = (tid & 3) * 4;
            float4 v = make_float4(0.f, 0.f, 0.f, 0.f);
            if (r < N) v = *reinterpret_cast<const float4*>(H + (size_t)r * 64 + k0 + cc);
            As[cc + 0][tid >> 2] = v.x;
            As[cc + 1][tid >> 2] = v.y;
            As[cc + 2][tid >> 2] = v.z;
            As[cc + 3][tid >> 2] = v.w;
        }
        {
            int rr = tid >> 4;
            int cc = (tid & 15) * 4;
            float4 v = *reinterpret_cast<const float4*>(Wk + (k0 + rr) * 64 + cc);
            if (by == 0) {
                float4 w2 = *reinterpret_cast<const float4*>(W2k + (k0 + rr) * 64 + cc);
                v.x -= w2.x; v.y -= w2.y; v.z -= w2.z; v.w -= w2.w;
            }
            *reinterpret_cast<float4*>(&Bs[rr][cc]) = v;
        }
        __syncthreads();
#pragma unroll
        for (int kk = 0; kk < 16; ++kk) {
            float4 a = *reinterpret_cast<const float4*>(&As[kk][tr * 4]);
            float4 b = *reinterpret_cast<const float4*>(&Bs[kk][tc * 4]);
            acc[0][0] += a.x * b.x; acc[0][1] += a.x * b.y; acc[0][2] += a.x * b.z; acc[0][3] += a.x * b.w;
            acc[1][0] += a.y * b.x; acc[1][1] += a.y * b.y; acc[1][2] += a.y * b.z; acc[1][3] += a.y * b.w;
            acc[2][0] += a.z * b.x; acc[2][1] += a.z * b.y; acc[2][2] += a.z * b.z; acc[2][3] += a.z * b.w;
            acc[3][0] += a.w * b.x; acc[3][1] += a.w * b.y; acc[3][2] += a.w * b.z; acc[3][3] += a.w * b.w;
        }
        __syncthreads();
    }
    int cbase = by * 64;
#pragma unroll
    for (int i = 0; i < 4; ++i) {
        int r = row0 + tr * 4 + i;
        if (r >= N) continue;
#pragma unroll
        for (int j = 0; j < 4; ++j)
            V[(size_t)r * 192 + cbase + tc * 4 + j] = acc[i][j];
    }
}

// ====== 3-term GEMM + pool (layer 3): relu(T0@W0+T1@W1+T2@W2+b) -> sums =====
__global__ __launch_bounds__(256) void k_gemm3p(const float* __restrict__ T0,
                                                const float* __restrict__ T1,
                                                const float* __restrict__ T2,
                                                const float* __restrict__ W,
                                                const float* __restrict__ bias,
                                                int N, int Fin, int Fout,
                                                const int* __restrict__ batch,
                                                float* __restrict__ sums) {
    __shared__ float As[16][68];
    __shared__ float Bs[16][64];
    int row0 = blockIdx.x * 64;
    int col0 = blockIdx.y * 64;
    int tid = threadIdx.x;
    int tr = tid >> 4, tc = tid & 15;
    float acc[4][4] = {};
    const float* Ts[3] = {T0, T1, T2};
    for (int k = 0; k < 3; ++k) {
        const float* T = Ts[k];
        const float* Wk = W + k * Fin * Fout;
        for (int k0 = 0; k0 < Fin; k0 += 16) {
            {
                int r = row0 + (tid >> 2);
                int cc = (tid & 3) * 4;
                float4 v = make_float4(0.f, 0.f, 0.f, 0.f);
                if (r < N)
                    v = *reinterpret_cast<const float4*>(T + (size_t)r * Fin + k0 + cc);
                As[cc + 0][tid >> 2] = v.x;
                As[cc + 1][tid >> 2] = v.y;
                As[cc + 2][tid >> 2] = v.z;
                As[cc + 3][tid >> 2] = v.w;
            }
            {
                int rr = tid >> 4;
                int cc = (tid & 15) * 4;
                *reinterpret_cast<float4*>(&Bs[rr][cc]) =
                    *reinterpret_cast<const float4*>(Wk + (size_t)(k0 + rr) * Fout + col0 + cc);
            }
            __syncthreads();
#pragma unroll
            for (int kk = 0; kk < 16; ++kk) {
                float4 a = *reinterpret_cast<const float4*>(&As[kk][tr * 4]);
                float4 b = *reinterpret_cast<const float4*>(&Bs[kk][tc * 4]);
                acc[0][0] += a.x * b.x; acc[0][1] += a.x * b.y; acc[0][2] += a.x * b.z; acc[0][3] += a.x * b.w;
                acc[1][0] += a.y * b.x; acc[1][1] += a.y * b.y; acc[1][2] += a.y * b.z; acc[1][3] += a.y * b.w;
                acc[2][0] += a.z * b.x; acc[2][1] += a.z * b.y; acc[2][2] += a.z * b.z; acc[2][3] += a.z * b.w;
                acc[3][0] += a.w * b.x; acc[3][1] += a.w * b.y; acc[3][2] += a.w * b.z; acc[3][3] += a.w * b.w;
            }
            __syncthreads();
        }
    }
    __shared__ float ps[64];
    int b0 = batch[row0];
    int b1v = batch[min(row0 + 63, N - 1)];
    if (b0 == b1v) {
        if (tid < 64) ps[tid] = 0.f;
        __syncthreads();
#pragma unroll
        for (int j = 0; j < 4; ++j) {
            float cs = 0.f;
#pragma unroll
            for (int i = 0; i < 4; ++i) {
                int r = row0 + tr * 4 + i;
                if (r < N) cs += fmaxf(acc[i][j] + bias[col0 + tc * 4 + j], 0.f);
            }
            atomicAdd(&ps[tc * 4 + j], cs);
        }
        __syncthreads();
        if (tid < 64) atomicAdd(&sums[b0 * 128 + col0 + tid], ps[tid]);
    } else {
#pragma unroll
        for (int i = 0; i < 4; ++i) {
            int r = row0 + tr * 4 + i;
            if (r >= N) continue;
#pragma unroll
            for (int j = 0; j < 4; ++j) {
                int cgl = col0 + tc * 4 + j;
                float v = fmaxf(acc[i][j] + bias[cgl], 0.f);
                atomicAdd(&sums[batch[r] * 128 + cgl], v);
            }
        }
    }
}

// ================= head (graph starts computed in-kernel) =================
__global__ __launch_bounds__(640) void k_head(const float* __restrict__ sums,
                                              const int* __restrict__ batch, int N,
                                              const float* __restrict__ linW,
                                              const float* __restrict__ linb,
                                              float* __restrict__ out) {
    __shared__ int st[65];
    int t = threadIdx.x;
    if (t <= 64) {
        if (t == 64) {
            st[64] = N;
        } else {
            int lo = 0, hi = N;
            while (lo < hi) {
                int mid = (lo + hi) >> 1;
                if (batch[mid] < t) lo = mid + 1; else hi = mid;
            }
            st[t] = lo;
        }
    }
    __syncthreads();
    if (t >= NG * 10) return;
    int g = t / 10, o = t % 10;
    float cnt = (float)(st[g + 1] - st[g]);
    float inv = 1.f / fmaxf(cnt, 1.f);
    float acc = 0.f;
#pragma unroll 8
    for (int k = 0; k < 128; ++k) acc += sums[g * 128 + k] * linW[k * 10 + o];
    out[t] = acc * inv + linb[o];
}

// ================= launch =================
extern "C" void kernel_launch(void* const* d_in, const int* in_sizes, int n_in,
                              void* d_out, int out_size, void* d_ws, size_t ws_size,
                              hipStream_t stream) {
    const float* x = (const float*)d_in[0];
    const int* ei = (const int*)d_in[1];
    const float* ew = (const float*)d_in[2];
    const int* batch = (const int*)d_in[3];
    const float* W1 = (const float*)d_in[4];
    const float* b1 = (const float*)d_in[5];
    const float* W2 = (const float*)d_in[6];
    const float* b2 = (const float*)d_in[7];
    const float* W3 = (const float*)d_in[8];
    const float* b3 = (const float*)d_in[9];
    const float* linW = (const float*)d_in[10];
    const float* linb = (const float*)d_in[11];

    const int E = in_sizes[1] / 2;   // 1,600,000
    const int N = in_sizes[0] / 128; // 100,000
    const int* src = ei;
    const int* dst = ei + E;

    float* ws = (float*)d_ws;
    int2*  csr     = (int2*)ws;                        // E entries -> 3,200,512 f
    int*   rank    = (int*)(ws + 3200512);             // 1,600,256
    int*   cursor  = rank + 1600256;                   // N+1 -> 100,352 (starts)
    float* dinv    = (float*)(cursor + 100352);        // 100,352 (deg then dinv)
    int*   bsum    = (int*)(dinv + 100352);            // 256
    int*   boff    = bsum + 256;                       // 256
    float* U       = (float*)(boff + 256);             // 19,200,256 (N x 192; V reuses)
    float* R       = U + 19200256;                     // 6,400,256 (R1/R2, then A3)
    float* H1      = R + 6400256;                      // 6,400,256
    float* H2      = H1 + 6400256;                     // 6,400,256
    float* B3      = H2 + 6400256;                     // 6,400,256
    float* sums    = B3 + 6400256;                     // 8,192

    float* A3 = R;

    const int TB = 256;
    auto blocks = [](long long t, int b) { return (int)((t + b - 1) / b); };
    const int PG64 = blocks((long long)N * 16, TB);
    const int NB = (N + 1023) / 1024;       // scan blocks
    const int GX = (N + 63) / 64;           // gemm x-blocks
    const int EB = blocks(E, TB);           // edge blocks

    // ---- memsets up front (cursor[N+1] + deg contiguous; sums) ----
    hipMemsetAsync(cursor, 0, (100352 + 100352) * sizeof(int), stream);
    hipMemsetAsync(sums, 0, NG * 128 * sizeof(float), stream);

    // ---- pre1: gemmU(y0,y1,y2) first, then edges (deg + hist + rank) ----
    k_pre1<<<3 * GX + EB, TB, 0, stream>>>(x, W1, U, N, src, dst, ew,
                                           dinv, cursor, rank, E, GX);
    // ---- dinv + scan (cursor -> row starts; cursor[N]=E) ----
    k_scan_a<<<NB, 1024, 0, stream>>>(cursor, bsum, dinv, N);
    k_scan_b<<<1, 128, 0, stream>>>(bsum, boff, NB);
    k_scan_c<<<NB, 1024, 0, stream>>>(cursor, boff, N, E);
    // ---- fill (no atomics) ----
    k_fill<<<EB, TB, 0, stream>>>(src, dst, ew, dinv, cursor, rank, csr, E);

    // ---- layer 1: R = U1 + 2*L(U2); H1 = relu(U0' + L(R) + b1) ----
    k_prop64<3><<<PG64, TB, 0, stream>>>(cursor, csr, U + 128, 192, R,
                                         U + 64, 192, nullptr, N);
    k_prop64<4><<<PG64, TB, 0, stream>>>(cursor, csr, R, 64, H1,
                                         U, 192, b1, N);

    // ---- layer 2: V = H1@[W0-W2|W1|W2]; R = V1 + 2*L(V2); H2 = relu(V0'+L(R)+b2)
    {
        dim3 g(GX, 3);
        k_gemmD<<<g, TB, 0, stream>>>(H1, W2, U, N);
    }
    k_prop64<3><<<PG64, TB, 0, stream>>>(cursor, csr, U + 128, 192, R,
                                         U + 64, 192, nullptr, N);
    k_prop64<4><<<PG64, TB, 0, stream>>>(cursor, csr, R, 64, H2,
                                         U, 192, b2, N);

    // ---- layer 3: A3 = L(H2); B3 = 2*L(A3) - H2; gemm3+pool ----
    k_prop64<0><<<PG64, TB, 0, stream>>>(cursor, csr, H2, 64, A3,
                                         nullptr, 0, nullptr, N);
    k_prop64<1><<<PG64, TB, 0, stream>>>(cursor, csr, A3, 64, B3,
                                         H2, 64, nullptr, N);
    {
        dim3 g(GX, 2);
        k_gemm3p<<<g, TB, 0, stream>>>(H2, A3, B3, W3, b3, N, 64, 128, batch, sums);
    }

    // ---- head ----
    k_head<<<1, 640, 0, stream>>>(sums, batch, N, linW, linb, (float*)d_out);
}